// Round 15
// baseline (644.485 us; speedup 1.0000x reference)
//
#include <hip/hip_runtime.h>
#include <hip/hip_bf16.h>

namespace {

constexpr int TT = 150;

__device__ __forceinline__ float dot4(float4 a, float4 b) {
  return a.x*b.x + a.y*b.y + a.z*b.z + a.w*b.w;
}
__device__ __forceinline__ unsigned short bf16bits(float v) {
  __hip_bfloat16 h = __float2bfloat16(v);
  return *reinterpret_cast<unsigned short*>(&h);
}
// f32 += dot of a bf16 pair (packed u32) with a bf16 pair (packed u32)
__device__ __forceinline__ float dot2bf(unsigned a, unsigned b, float c) {
  float d;
  asm("v_dot2_f32_bf16 %0, %1, %2, %3" : "=v"(d) : "v"(a), "v"(b), "v"(c));
  return d;
}
// 16-wide bf16 dot: two uint4 slots (k 0..7, 8..15) against cepk[0..7]
__device__ __forceinline__ float tdot(uint4 a, uint4 b, const unsigned* cp) {
  float s = 0.f;
  s = dot2bf(a.x, cp[0], s); s = dot2bf(a.y, cp[1], s);
  s = dot2bf(a.z, cp[2], s); s = dot2bf(a.w, cp[3], s);
  s = dot2bf(b.x, cp[4], s); s = dot2bf(b.y, cp[5], s);
  s = dot2bf(b.z, cp[6], s); s = dot2bf(b.w, cp[7], s);
  return s;
}

// t-build + banded matvec partials for d in [D0, D0+ND)
template<int D0, int ND>
__device__ __forceinline__ void tmv_part(const uint4* m4u, const unsigned* cepk,
                                         const float* stat, int ii, int b, int swz,
                                         float rv[5]) {
  #pragma unroll
  for (int dd = 0; dd < ND; ++dd) {
    const int d = D0 + dd;
    const int ba = (0*7 + d)*120 + ii*2;
    const int bb = (1*7 + d)*120 + ii*2;
    const int bc = (2*7 + d)*120 + ii*2;
    const int bd = (3*7 + d)*120 + ii*2;
    const uint4 xa = m4u[ba + swz], ya = m4u[ba + 1 - swz];
    const uint4 xb = m4u[bb + swz], yb = m4u[bb + 1 - swz];
    const uint4 xc = m4u[bc + swz], yc = m4u[bc + 1 - swz];
    const uint4 xd = m4u[bd + swz], yd = m4u[bd + 1 - swz];
    const float a11 = tdot(xa, ya, cepk);
    const float a12 = tdot(xb, yb, cepk);
    const float a21 = tdot(xc, yc, cepk);
    const float a22 = tdot(xd, yd, cepk);
    const int si = (ii + d)*4 + b;
    const float mun  = stat[si];
    const float mln  = stat[288  + si];
    const float pcun = stat[576  + si];
    const float pcsn = stat[864  + si];
    const float pcln = stat[1152 + si];
    rv[0] += a11*mun + a12*mln;
    rv[1] += a21*mun + a22*mln;
    rv[2] += a11*a11*pcun + 2.f*a11*a12*pcsn + a12*a12*pcln;
    rv[3] += a21*a21*pcun + 2.f*a21*a22*pcsn + a22*a22*pcln;
    rv[4] += a21*a11*pcun + (a22*a11 + a21*a12)*pcsn + a22*a12*pcln;
  }
}

// ---------------- single fused kernel (round-11 structure + input prefetch) ----
// 1024 threads = 16 waves, 4/SIMD. chunk = w>>2:
//   c0: front (Kalman/stat/logits->parts) + t-build d{0,1} + carries
//   c1: ctrl cols 0..59 (phase A) + t-build d{2,3}
//   c2: ctrl cols 60..119 (phase A) + t-build d{4,5}
//   c3: o0..o3 stores (post-B1) + t-build d{6} + o4..o7 stores
// 2 barriers/step. NEW vs round 14: lob/ovr/actp software-pipelined by one
// step in registers (issue t+1 loads at top of phase A(t)) — hides first-touch
// global latency under the step's compute. Register-only change.
__launch_bounds__(1024, 4)
__global__ void acrkn(const float* __restrict__ lob,   // (B,T,60)
                      const float* __restrict__ ovr,   // (B,T,60)
                      const float* __restrict__ actp,  // (B,T,10)
                      const float* __restrict__ im,    // (B,120)
                      const float* __restrict__ icu,   // (B,60)
                      const float* __restrict__ icl,   // (B,60)
                      const float* __restrict__ ics,   // (B,60)
                      const float* __restrict__ tm11,  // (15,60,60)
                      const float* __restrict__ tm12,
                      const float* __restrict__ tm21,
                      const float* __restrict__ tm22,
                      const float* __restrict__ cw,    // (120,15)
                      const float* __restrict__ cb,    // (15)
                      const float* __restrict__ w1,    // (10,60)
                      const float* __restrict__ b1,    // (60)
                      const float* __restrict__ w2,    // (60,120)
                      const float* __restrict__ b2,    // (120)
                      const float* __restrict__ ltc,   // (120)
                      float* __restrict__ out)
{
  __shared__ __align__(16) unsigned m4b[13440];   // basis bf16x2 (53760 B)
  __shared__ __align__(16) float cwc[2048];       // logits weights (f4 = c*128+p)
  __shared__ __align__(16) float stat[1440];      // [vec][row 0..71][b]
  __shared__ __align__(16) float parts[256];      // [wq][b][k16]
  __shared__ __align__(16) float red[5120];       // [chunk][v][i<64][b]
  __shared__ __align__(16) float ctl[1056];       // [par][b][132] padded
  __shared__ __align__(16) float hctl[512];       // [w-4][j<64]
  __shared__ __align__(16) float w2T[7680];       // [col<128][j4<15][e]
  __shared__ float w1s[640];                      // [a][j<64]
  __shared__ float b1s[64];
  __shared__ float b2s[128];
  __shared__ float cbs[16];

  const int tid = threadIdx.x;

  // ---------------- one-time LDS staging ----------------
  for (int idx = tid; idx < 13440; idx += 1024) {
    const int c2 = idx & 7;
    int rest = idx >> 3;
    const int i = rest % 60;  rest /= 60;
    const int d = rest % 7;
    const int mat = rest / 7;
    const int k0 = 2*c2;
    const int j = i + d - 3;
    const float* tp = (mat == 0) ? tm11 : (mat == 1) ? tm12 : (mat == 2) ? tm21 : tm22;
    float ve = 0.f, vo = 0.f;
    if (j >= 0 && j < 60) {
      ve = tp[(k0*60 + i)*60 + j];
      if (k0 + 1 < 15) vo = tp[((k0+1)*60 + i)*60 + j];
    }
    const unsigned u = ((unsigned)bf16bits(vo) << 16) | (unsigned)bf16bits(ve);
    const int s = c2 >> 2, q = c2 & 3;
    const int sp = s ^ ((i >> 2) & 1);
    m4b[(((mat*7 + d)*60 + i)*2 + sp)*4 + q] = u;
  }
  if (tid < 512) {
    const int f4 = tid;
    const int p = f4 & 127, c = f4 >> 7;
    const int col = (p < 60) ? p : ((p >= 64 && p < 124) ? (p - 4) : -1);
    float v0 = 0.f, v1 = 0.f, v2 = 0.f, v3 = 0.f;
    if (col >= 0) {
      const int k0 = c*4;
      v0 = cw[col*15 + k0+0];
      v1 = cw[col*15 + k0+1];
      v2 = cw[col*15 + k0+2];
      v3 = (k0+3 < 15) ? cw[col*15 + k0+3] : 0.f;
    }
    ((float4*)cwc)[f4] = make_float4(v0, v1, v2, v3);
  }
  for (int idx = tid; idx < 7680; idx += 1024) {
    const int e = idx & 3;
    const int f4 = idx >> 2;
    const int j4 = f4 % 15;
    const int col = f4 / 15;
    const int j = 4*j4 + e;
    w2T[idx] = (j < 60 && col < 120) ? w2[j*120 + col] : 0.f;
  }
  for (int idx = tid; idx < 640; idx += 1024) {
    const int j = idx & 63, a = idx >> 6;
    w1s[idx] = (j < 60) ? w1[a*60 + j] : 0.f;
  }
  for (int idx = tid; idx < 1440; idx += 1024) stat[idx] = 0.f;
  if (tid < 64)  b1s[tid] = (tid < 60)  ? b1[tid] : 0.f;
  if (tid < 128) b2s[tid] = (tid < 120) ? b2[tid] : 0.f;
  if (tid < 16)  cbs[tid] = (tid < 15)  ? cb[tid] : 0.f;

  const int w = tid >> 6;
  const int chunk = w >> 2;
  const int wq = w & 3;
  const int lane = tid & 63;
  const int r = lane >> 2;
  const int b = lane & 3;
  const int iraw = wq*16 + r;
  const bool valid = (iraw < 60);
  const int ii = valid ? iraw : 0;
  const int gb = blockIdx.x*4 + b;
  const int swz = (ii >> 2) & 1;

  // carries (front only reads them)
  float mu_c = 0.f, ml_c = 0.f, cu_c = 1.f, cl_c = 1.f, cs_c = 0.f;
  float tcu_r = 1.f, tcl_r = 1.f;
  if (valid) {
    mu_c = im[gb*120 + ii];
    ml_c = im[gb*120 + 60 + ii];
    cu_c = icu[gb*60 + ii];
    cl_c = icl[gb*60 + ii];
    cs_c = ics[gb*60 + ii];
    const float l0 = ltc[ii], l1 = ltc[60 + ii];
    tcu_r = (l0 >= 0.f) ? l0 + 1.f : __expf(l0);   // elup1
    tcl_r = (l1 >= 0.f) ? l1 + 1.f : __expf(l1);
  }

  // prefetch registers for the t=0 inputs (issued here so the load overlaps
  // the LDS staging + initial barrier)
  float obs_c = 0.f, ovv_c = 1.f, av_c = 0.f;
  if (chunk == 0) {
    if (valid) {
      const long ib0 = (long)gb*(TT*60) + ii;
      obs_c = lob[ib0];
      ovv_c = ovr[ib0];
    }
  } else if (chunk == 1 || chunk == 2) {
    if (lane < 10) {
      const int gbc0 = blockIdx.x*4 + wq;
      av_c = actp[(long)gbc0*(TT*10) + lane];
    }
  }

  const uint4*  m4u    = (const uint4*)m4b;
  const float4* cwc4   = (const float4*)cwc;
  const float4* parts4 = (const float4*)parts;

  float* o0 = out;                 // post_means  (B,T,120)
  float* o1 = out + 18432000L;     // pcu (B,T,60)
  float* o2 = out + 27648000L;     // pcl
  float* o3 = out + 36864000L;     // pcs
  float* o4 = out + 46080000L;     // prior_means (B,T,120)
  float* o5 = out + 64512000L;     // ncu
  float* o6 = out + 73728000L;     // ncl
  float* o7 = out + 82944000L;     // ncs

  __syncthreads();

  for (int t = 0; t < TT; ++t) {
    const int par = t & 1;

    // ---- phase A ----
    if (chunk == 0) {
      // issue t+1 input loads FIRST (independent of carries; latency hidden
      // under this whole step) ...
      float obs_n = 0.f, ovv_n = 1.f;
      if (valid && t + 1 < TT) {
        const long ibn = (long)gb*(TT*60) + (t+1)*60 + ii;
        obs_n = lob[ibn];
        ovv_n = ovr[ibn];
      }
      // ... then the Kalman update consumes the prefetched current values
      const float obs = obs_c, ovv = ovv_c;
      const float denom = cu_c + ovv;
      const float inv = 1.0f / denom;
      const float qu = cu_c * inv;
      const float ql = cs_c * inv;
      const float res = obs - mu_c;
      float pm_u = mu_c + qu*res;
      float pm_l = ml_c + ql*res;
      const float f1 = 1.f - qu;
      float pcu = f1*cu_c, pcs = f1*cs_c, pcl = cl_c - ql*cs_c;
      if (!valid) { pm_u = 0.f; pm_l = 0.f; pcu = 0.f; pcs = 0.f; pcl = 0.f; }

      if (valid) {
        stat[(0*72 + ii + 3)*4 + b] = pm_u;
        stat[(1*72 + ii + 3)*4 + b] = pm_l;
        stat[(2*72 + ii + 3)*4 + b] = pcu;
        stat[(3*72 + ii + 3)*4 + b] = pcs;
        stat[(4*72 + ii + 3)*4 + b] = pcl;
      }

      float p[16];
      #pragma unroll
      for (int k = 0; k < 16; ++k) p[k] = 0.f;
      #pragma unroll
      for (int c = 0; c < 4; ++c) {
        const float4 wu = cwc4[c*128 + ii];
        const float4 wl = cwc4[c*128 + 64 + ii];
        p[c*4+0] += pm_u*wu.x + pm_l*wl.x;
        p[c*4+1] += pm_u*wu.y + pm_l*wl.y;
        p[c*4+2] += pm_u*wu.z + pm_l*wl.z;
        p[c*4+3] += pm_u*wu.w + pm_l*wl.w;
      }
      // halving butterfly over r-lanes (lane bits 2..5); b (bits 0..1) preserved.
      float s1[8];
      #pragma unroll
      for (int k = 0; k < 8; ++k) {
        const float send = (lane & 4) ? p[k] : p[k + 8];
        const float recv = __shfl_xor(send, 4);
        s1[k] = ((lane & 4) ? p[k + 8] : p[k]) + recv;
      }
      float s2[4];
      #pragma unroll
      for (int k = 0; k < 4; ++k) {
        const float send = (lane & 8) ? s1[k] : s1[k + 4];
        const float recv = __shfl_xor(send, 8);
        s2[k] = ((lane & 8) ? s1[k + 4] : s1[k]) + recv;
      }
      float s3[2];
      #pragma unroll
      for (int k = 0; k < 2; ++k) {
        const float send = (lane & 16) ? s2[k] : s2[k + 2];
        const float recv = __shfl_xor(send, 16);
        s3[k] = ((lane & 16) ? s2[k + 2] : s2[k]) + recv;
      }
      const float send4 = (lane & 32) ? s3[0] : s3[1];
      const float recv4 = __shfl_xor(send4, 32);
      const float stot = ((lane & 32) ? s3[1] : s3[0]) + recv4;
      const int kf = ((r & 1) << 3) | ((r & 2) << 1) | ((r & 4) >> 1) | ((r & 8) >> 3);
      parts[(wq*4 + b)*16 + kf] = stot;   // 64 distinct words -> conflict-free

      // rotate prefetch registers
      obs_c = obs_n; ovv_c = ovv_n;
    } else if (chunk == 1 || chunk == 2) {
      // ctrl MLP for batch slot wq, this chunk's column half; lane = j / col
      const int gbc = blockIdx.x*4 + wq;
      // issue t+1 action load first
      float av_n = 0.f;
      if (lane < 10 && t + 1 < TT) av_n = actp[((long)gbc*TT + t + 1)*10 + lane];
      const float av = av_c;
      float hj = b1s[lane];
      #pragma unroll
      for (int a = 0; a < 10; ++a) hj += __shfl(av, a) * w1s[a*64 + lane];
      const int hw = w - 4;
      hctl[hw*64 + lane] = (lane < 60) ? fmaxf(hj, 0.f) : 0.f;
      const int col = (chunk == 1) ? lane : 60 + lane;
      float s = (lane < 60) ? b2s[col] : 0.f;
      const float4* hb4c = (const float4*)&hctl[hw*64];
      #pragma unroll
      for (int j4 = 0; j4 < 15; ++j4)
        s += dot4(hb4c[j4], *(const float4*)&w2T[col*60 + j4*4]);
      if (lane < 60) ctl[par*528 + wq*132 + col] = s;
      av_c = av_n;
    }
    // c3 idle in phase A
    __syncthreads();   // B1

    // ---- c3: store post_means/post_covs from stat ----
    if (chunk == 3 && valid) {
      const long ob120 = ((long)gb*TT + t)*120;
      const long ob60  = ((long)gb*TT + t)*60;
      o0[ob120 + ii]      = stat[(0*72 + ii + 3)*4 + b];
      o0[ob120 + 60 + ii] = stat[(1*72 + ii + 3)*4 + b];
      o1[ob60 + ii] = stat[(2*72 + ii + 3)*4 + b];
      o3[ob60 + ii] = stat[(3*72 + ii + 3)*4 + b];
      o2[ob60 + ii] = stat[(4*72 + ii + 3)*4 + b];
    }

    // ---- softmax (all waves, redundant per b; fixed-order read-sum) ----
    float q[16];
    #pragma unroll
    for (int k = 0; k < 16; ++k) q[k] = cbs[k];
    #pragma unroll
    for (int ww = 0; ww < 4; ++ww) {
      #pragma unroll
      for (int c = 0; c < 4; ++c) {
        const float4 pv = parts4[(ww*4 + b)*4 + c];
        q[4*c+0] += pv.x; q[4*c+1] += pv.y; q[4*c+2] += pv.z; q[4*c+3] += pv.w;
      }
    }
    float ce[16];
    #pragma unroll
    for (int k = 0; k < 15; ++k) ce[k] = __expf(q[k]);
    const float e0 = (ce[0]+ce[1]) + (ce[2]+ce[3]);
    const float e1 = (ce[4]+ce[5]) + (ce[6]+ce[7]);
    const float e2 = (ce[8]+ce[9]) + (ce[10]+ce[11]);
    const float e3 = (ce[12]+ce[13]) + ce[14];
    const float rs = 1.f / ((e0+e1) + (e2+e3));
    #pragma unroll
    for (int k = 0; k < 15; ++k) ce[k] *= rs;
    ce[15] = 0.f;
    unsigned cepk[8];
    #pragma unroll
    for (int j = 0; j < 8; ++j)
      cepk[j] = ((unsigned)bf16bits(ce[2*j+1]) << 16) | (unsigned)bf16bits(ce[2*j]);

    // ---- t-build + matvec partials, d-range per chunk ----
    float rv[5] = {0.f, 0.f, 0.f, 0.f, 0.f};
    if      (chunk == 0) tmv_part<0, 2>(m4u, cepk, stat, ii, b, swz, rv);
    else if (chunk == 1) tmv_part<2, 2>(m4u, cepk, stat, ii, b, swz, rv);
    else if (chunk == 2) tmv_part<4, 2>(m4u, cepk, stat, ii, b, swz, rv);
    else                 tmv_part<6, 1>(m4u, cepk, stat, ii, b, swz, rv);

    if (valid) {
      #pragma unroll
      for (int v = 0; v < 5; ++v) red[chunk*1280 + v*256 + ii*4 + b] = rv[v];
    }
    __syncthreads();   // B2

    // ---- combine (front: carries; c3: stores o4..o7) ----
    if (chunk == 0 || chunk == 3) {
      const float ctrl_u = ctl[par*528 + b*132 + ii];
      const float ctrl_l = ctl[par*528 + b*132 + 60 + ii];
      const int rb = ii*4 + b;
      float nmu = ctrl_u, nml = ctrl_l, ncu = tcu_r, ncl = tcl_r, ncs = 0.f;
      #pragma unroll
      for (int c = 0; c < 4; ++c) {
        nmu += red[c*1280 + 0*256 + rb];
        nml += red[c*1280 + 1*256 + rb];
        ncu += red[c*1280 + 2*256 + rb];
        ncl += red[c*1280 + 3*256 + rb];
        ncs += red[c*1280 + 4*256 + rb];
      }
      if (chunk == 3) {
        if (valid) {
          const long ob120 = ((long)gb*TT + t)*120;
          const long ob60  = ((long)gb*TT + t)*60;
          o4[ob120 + ii]      = nmu;
          o4[ob120 + 60 + ii] = nml;
          o5[ob60 + ii] = ncu;
          o6[ob60 + ii] = ncl;
          o7[ob60 + ii] = ncs;
        }
      } else {
        mu_c = nmu; ml_c = nml; cu_c = ncu; cl_c = ncl; cs_c = ncs;
      }
    }
    // races (proven in rounds 8/11/14): stat written pre-B1(t), read until
    // B2(t), next write after B2(t); parts written pre-B1(t), read pre-B2(t),
    // next write after B2(t); ctl parity-buffered; red written pre-B2(t),
    // read post-B2(t), next write after B1(t+1). Prefetch regs are
    // thread-private — no new shared state.
  }
}

} // namespace

extern "C" void kernel_launch(void* const* d_in, const int* in_sizes, int n_in,
                              void* d_out, int out_size, void* d_ws, size_t ws_size,
                              hipStream_t stream) {
  (void)in_sizes; (void)n_in; (void)d_ws; (void)ws_size; (void)out_size;
  const float* lob  = (const float*)d_in[0];
  const float* ovr  = (const float*)d_in[1];
  const float* actp = (const float*)d_in[2];
  const float* im   = (const float*)d_in[3];
  const float* icu  = (const float*)d_in[4];
  const float* icl  = (const float*)d_in[5];
  const float* ics  = (const float*)d_in[6];
  const float* tm11 = (const float*)d_in[7];
  const float* tm12 = (const float*)d_in[8];
  const float* tm21 = (const float*)d_in[9];
  const float* tm22 = (const float*)d_in[10];
  const float* cw   = (const float*)d_in[11];
  const float* cb   = (const float*)d_in[12];
  const float* w1   = (const float*)d_in[13];
  const float* b1   = (const float*)d_in[14];
  const float* w2   = (const float*)d_in[15];
  const float* b2   = (const float*)d_in[16];
  const float* ltc  = (const float*)d_in[17];

  acrkn<<<dim3(256), dim3(1024), 0, stream>>>(
      lob, ovr, actp, im, icu, icl, ics,
      tm11, tm12, tm21, tm22, cw, cb, w1, b1, w2, b2, ltc,
      (float*)d_out);
}

// Round 16
// 620.084 us; speedup vs baseline: 1.0394x; 1.0394x over previous
//
#include <hip/hip_runtime.h>
#include <hip/hip_bf16.h>

namespace {

constexpr int TT = 150;

__device__ __forceinline__ float dot4(float4 a, float4 b) {
  return a.x*b.x + a.y*b.y + a.z*b.z + a.w*b.w;
}
__device__ __forceinline__ unsigned short bf16bits(float v) {
  __hip_bfloat16 h = __float2bfloat16(v);
  return *reinterpret_cast<unsigned short*>(&h);
}
// f32 += dot of a bf16 pair (packed u32) with a bf16 pair (packed u32)
__device__ __forceinline__ float dot2bf(unsigned a, unsigned b, float c) {
  float d;
  asm("v_dot2_f32_bf16 %0, %1, %2, %3" : "=v"(d) : "v"(a), "v"(b), "v"(c));
  return d;
}
// 16-wide bf16 dot: two uint4 slots (k 0..7, 8..15) against cepk[0..7]
__device__ __forceinline__ float tdot(uint4 a, uint4 b, const unsigned* cp) {
  float s = 0.f;
  s = dot2bf(a.x, cp[0], s); s = dot2bf(a.y, cp[1], s);
  s = dot2bf(a.z, cp[2], s); s = dot2bf(a.w, cp[3], s);
  s = dot2bf(b.x, cp[4], s); s = dot2bf(b.y, cp[5], s);
  s = dot2bf(b.z, cp[6], s); s = dot2bf(b.w, cp[7], s);
  return s;
}

// t-build + banded matvec partials for d in [D0, D0+ND)
template<int D0, int ND>
__device__ __forceinline__ void tmv_part(const uint4* m4u, const unsigned* cepk,
                                         const float* stat, int ii, int b, int swz,
                                         float rv[5]) {
  #pragma unroll
  for (int dd = 0; dd < ND; ++dd) {
    const int d = D0 + dd;
    const int ba = (0*7 + d)*120 + ii*2;
    const int bb = (1*7 + d)*120 + ii*2;
    const int bc = (2*7 + d)*120 + ii*2;
    const int bd = (3*7 + d)*120 + ii*2;
    const uint4 xa = m4u[ba + swz], ya = m4u[ba + 1 - swz];
    const uint4 xb = m4u[bb + swz], yb = m4u[bb + 1 - swz];
    const uint4 xc = m4u[bc + swz], yc = m4u[bc + 1 - swz];
    const uint4 xd = m4u[bd + swz], yd = m4u[bd + 1 - swz];
    const float a11 = tdot(xa, ya, cepk);
    const float a12 = tdot(xb, yb, cepk);
    const float a21 = tdot(xc, yc, cepk);
    const float a22 = tdot(xd, yd, cepk);
    const int si = (ii + d)*4 + b;
    const float mun  = stat[si];
    const float mln  = stat[288  + si];
    const float pcun = stat[576  + si];
    const float pcsn = stat[864  + si];
    const float pcln = stat[1152 + si];
    rv[0] += a11*mun + a12*mln;
    rv[1] += a21*mun + a22*mln;
    rv[2] += a11*a11*pcun + 2.f*a11*a12*pcsn + a12*a12*pcln;
    rv[3] += a21*a21*pcun + 2.f*a21*a22*pcsn + a22*a22*pcln;
    rv[4] += a21*a11*pcun + (a22*a11 + a21*a12)*pcsn + a22*a12*pcln;
  }
}

// ---------------- single fused kernel (round-11/14 proven configuration) ----
// 1024 threads = 16 waves, 4/SIMD. chunk = w>>2:
//   c0: front (Kalman/stat/logits->parts) + t-build d{0,1} + carries
//   c1: ctrl cols 0..59 (phase A) + t-build d{2,3}
//   c2: ctrl cols 60..119 (phase A) + t-build d{4,5}
//   c3: o0..o3 stores (post-B1) + t-build d{6} + o4..o7 stores
// 2 barriers/step; softmax redundant per wave. 623 us, absmax 0.015625.
__launch_bounds__(1024, 4)
__global__ void acrkn(const float* __restrict__ lob,   // (B,T,60)
                      const float* __restrict__ ovr,   // (B,T,60)
                      const float* __restrict__ actp,  // (B,T,10)
                      const float* __restrict__ im,    // (B,120)
                      const float* __restrict__ icu,   // (B,60)
                      const float* __restrict__ icl,   // (B,60)
                      const float* __restrict__ ics,   // (B,60)
                      const float* __restrict__ tm11,  // (15,60,60)
                      const float* __restrict__ tm12,
                      const float* __restrict__ tm21,
                      const float* __restrict__ tm22,
                      const float* __restrict__ cw,    // (120,15)
                      const float* __restrict__ cb,    // (15)
                      const float* __restrict__ w1,    // (10,60)
                      const float* __restrict__ b1,    // (60)
                      const float* __restrict__ w2,    // (60,120)
                      const float* __restrict__ b2,    // (120)
                      const float* __restrict__ ltc,   // (120)
                      float* __restrict__ out)
{
  __shared__ __align__(16) unsigned m4b[13440];   // basis bf16x2 (53760 B)
  __shared__ __align__(16) float cwc[2048];       // logits weights (f4 = c*128+p)
  __shared__ __align__(16) float stat[1440];      // [vec][row 0..71][b]
  __shared__ __align__(16) float parts[256];      // [wq][b][k16]
  __shared__ __align__(16) float red[5120];       // [chunk][v][i<64][b]
  __shared__ __align__(16) float ctl[1056];       // [par][b][132] padded
  __shared__ __align__(16) float hctl[512];       // [w-4][j<64]
  __shared__ __align__(16) float w2T[7680];       // [col<128][j4<15][e]
  __shared__ float w1s[640];                      // [a][j<64]
  __shared__ float b1s[64];
  __shared__ float b2s[128];
  __shared__ float cbs[16];

  const int tid = threadIdx.x;

  // ---------------- one-time LDS staging ----------------
  for (int idx = tid; idx < 13440; idx += 1024) {
    const int c2 = idx & 7;
    int rest = idx >> 3;
    const int i = rest % 60;  rest /= 60;
    const int d = rest % 7;
    const int mat = rest / 7;
    const int k0 = 2*c2;
    const int j = i + d - 3;
    const float* tp = (mat == 0) ? tm11 : (mat == 1) ? tm12 : (mat == 2) ? tm21 : tm22;
    float ve = 0.f, vo = 0.f;
    if (j >= 0 && j < 60) {
      ve = tp[(k0*60 + i)*60 + j];
      if (k0 + 1 < 15) vo = tp[((k0+1)*60 + i)*60 + j];
    }
    const unsigned u = ((unsigned)bf16bits(vo) << 16) | (unsigned)bf16bits(ve);
    const int s = c2 >> 2, q = c2 & 3;
    const int sp = s ^ ((i >> 2) & 1);
    m4b[(((mat*7 + d)*60 + i)*2 + sp)*4 + q] = u;
  }
  if (tid < 512) {
    const int f4 = tid;
    const int p = f4 & 127, c = f4 >> 7;
    const int col = (p < 60) ? p : ((p >= 64 && p < 124) ? (p - 4) : -1);
    float v0 = 0.f, v1 = 0.f, v2 = 0.f, v3 = 0.f;
    if (col >= 0) {
      const int k0 = c*4;
      v0 = cw[col*15 + k0+0];
      v1 = cw[col*15 + k0+1];
      v2 = cw[col*15 + k0+2];
      v3 = (k0+3 < 15) ? cw[col*15 + k0+3] : 0.f;
    }
    ((float4*)cwc)[f4] = make_float4(v0, v1, v2, v3);
  }
  for (int idx = tid; idx < 7680; idx += 1024) {
    const int e = idx & 3;
    const int f4 = idx >> 2;
    const int j4 = f4 % 15;
    const int col = f4 / 15;
    const int j = 4*j4 + e;
    w2T[idx] = (j < 60 && col < 120) ? w2[j*120 + col] : 0.f;
  }
  for (int idx = tid; idx < 640; idx += 1024) {
    const int j = idx & 63, a = idx >> 6;
    w1s[idx] = (j < 60) ? w1[a*60 + j] : 0.f;
  }
  for (int idx = tid; idx < 1440; idx += 1024) stat[idx] = 0.f;
  if (tid < 64)  b1s[tid] = (tid < 60)  ? b1[tid] : 0.f;
  if (tid < 128) b2s[tid] = (tid < 120) ? b2[tid] : 0.f;
  if (tid < 16)  cbs[tid] = (tid < 15)  ? cb[tid] : 0.f;

  const int w = tid >> 6;
  const int chunk = w >> 2;
  const int wq = w & 3;
  const int lane = tid & 63;
  const int r = lane >> 2;
  const int b = lane & 3;
  const int iraw = wq*16 + r;
  const bool valid = (iraw < 60);
  const int ii = valid ? iraw : 0;
  const int gb = blockIdx.x*4 + b;
  const int swz = (ii >> 2) & 1;

  // carries (front only reads them)
  float mu_c = 0.f, ml_c = 0.f, cu_c = 1.f, cl_c = 1.f, cs_c = 0.f;
  float tcu_r = 1.f, tcl_r = 1.f;
  if (valid) {
    mu_c = im[gb*120 + ii];
    ml_c = im[gb*120 + 60 + ii];
    cu_c = icu[gb*60 + ii];
    cl_c = icl[gb*60 + ii];
    cs_c = ics[gb*60 + ii];
    const float l0 = ltc[ii], l1 = ltc[60 + ii];
    tcu_r = (l0 >= 0.f) ? l0 + 1.f : __expf(l0);   // elup1
    tcl_r = (l1 >= 0.f) ? l1 + 1.f : __expf(l1);
  }

  const uint4*  m4u    = (const uint4*)m4b;
  const float4* cwc4   = (const float4*)cwc;
  const float4* parts4 = (const float4*)parts;

  float* o0 = out;                 // post_means  (B,T,120)
  float* o1 = out + 18432000L;     // pcu (B,T,60)
  float* o2 = out + 27648000L;     // pcl
  float* o3 = out + 36864000L;     // pcs
  float* o4 = out + 46080000L;     // prior_means (B,T,120)
  float* o5 = out + 64512000L;     // ncu
  float* o6 = out + 73728000L;     // ncl
  float* o7 = out + 82944000L;     // ncs

  __syncthreads();

  for (int t = 0; t < TT; ++t) {
    const int par = t & 1;

    // ---- phase A ----
    if (chunk == 0) {
      // front: Kalman + stat + logits partials + halving-butterfly reduce
      const long ib = (long)gb*(TT*60) + t*60 + ii;
      float obs = 0.f, ovv = 1.f;
      if (valid) { obs = lob[ib]; ovv = ovr[ib]; }
      const float denom = cu_c + ovv;
      const float inv = 1.0f / denom;
      const float qu = cu_c * inv;
      const float ql = cs_c * inv;
      const float res = obs - mu_c;
      float pm_u = mu_c + qu*res;
      float pm_l = ml_c + ql*res;
      const float f1 = 1.f - qu;
      float pcu = f1*cu_c, pcs = f1*cs_c, pcl = cl_c - ql*cs_c;
      if (!valid) { pm_u = 0.f; pm_l = 0.f; pcu = 0.f; pcs = 0.f; pcl = 0.f; }

      if (valid) {
        stat[(0*72 + ii + 3)*4 + b] = pm_u;
        stat[(1*72 + ii + 3)*4 + b] = pm_l;
        stat[(2*72 + ii + 3)*4 + b] = pcu;
        stat[(3*72 + ii + 3)*4 + b] = pcs;
        stat[(4*72 + ii + 3)*4 + b] = pcl;
      }

      float p[16];
      #pragma unroll
      for (int k = 0; k < 16; ++k) p[k] = 0.f;
      #pragma unroll
      for (int c = 0; c < 4; ++c) {
        const float4 wu = cwc4[c*128 + ii];
        const float4 wl = cwc4[c*128 + 64 + ii];
        p[c*4+0] += pm_u*wu.x + pm_l*wl.x;
        p[c*4+1] += pm_u*wu.y + pm_l*wl.y;
        p[c*4+2] += pm_u*wu.z + pm_l*wl.z;
        p[c*4+3] += pm_u*wu.w + pm_l*wl.w;
      }
      // halving butterfly over r-lanes (lane bits 2..5); b (bits 0..1) preserved.
      float s1[8];
      #pragma unroll
      for (int k = 0; k < 8; ++k) {
        const float send = (lane & 4) ? p[k] : p[k + 8];
        const float recv = __shfl_xor(send, 4);
        s1[k] = ((lane & 4) ? p[k + 8] : p[k]) + recv;
      }
      float s2[4];
      #pragma unroll
      for (int k = 0; k < 4; ++k) {
        const float send = (lane & 8) ? s1[k] : s1[k + 4];
        const float recv = __shfl_xor(send, 8);
        s2[k] = ((lane & 8) ? s1[k + 4] : s1[k]) + recv;
      }
      float s3[2];
      #pragma unroll
      for (int k = 0; k < 2; ++k) {
        const float send = (lane & 16) ? s2[k] : s2[k + 2];
        const float recv = __shfl_xor(send, 16);
        s3[k] = ((lane & 16) ? s2[k + 2] : s2[k]) + recv;
      }
      const float send4 = (lane & 32) ? s3[0] : s3[1];
      const float recv4 = __shfl_xor(send4, 32);
      const float stot = ((lane & 32) ? s3[1] : s3[0]) + recv4;
      const int kf = ((r & 1) << 3) | ((r & 2) << 1) | ((r & 4) >> 1) | ((r & 8) >> 3);
      parts[(wq*4 + b)*16 + kf] = stot;   // 64 distinct words -> conflict-free
    } else if (chunk == 1 || chunk == 2) {
      // ctrl MLP for batch slot wq, this chunk's column half; lane = j / col
      const int gbc = blockIdx.x*4 + wq;
      const float av = (lane < 10) ? actp[((long)gbc*TT + t)*10 + lane] : 0.f;
      float hj = b1s[lane];
      #pragma unroll
      for (int a = 0; a < 10; ++a) hj += __shfl(av, a) * w1s[a*64 + lane];
      const int hw = w - 4;
      hctl[hw*64 + lane] = (lane < 60) ? fmaxf(hj, 0.f) : 0.f;
      const int col = (chunk == 1) ? lane : 60 + lane;
      float s = (lane < 60) ? b2s[col] : 0.f;
      const float4* hb4c = (const float4*)&hctl[hw*64];
      #pragma unroll
      for (int j4 = 0; j4 < 15; ++j4)
        s += dot4(hb4c[j4], *(const float4*)&w2T[col*60 + j4*4]);
      if (lane < 60) ctl[par*528 + wq*132 + col] = s;
    }
    // c3 idle in phase A
    __syncthreads();   // B1

    // ---- c3: store post_means/post_covs from stat ----
    if (chunk == 3 && valid) {
      const long ob120 = ((long)gb*TT + t)*120;
      const long ob60  = ((long)gb*TT + t)*60;
      o0[ob120 + ii]      = stat[(0*72 + ii + 3)*4 + b];
      o0[ob120 + 60 + ii] = stat[(1*72 + ii + 3)*4 + b];
      o1[ob60 + ii] = stat[(2*72 + ii + 3)*4 + b];
      o3[ob60 + ii] = stat[(3*72 + ii + 3)*4 + b];
      o2[ob60 + ii] = stat[(4*72 + ii + 3)*4 + b];
    }

    // ---- softmax (all waves, redundant per b; fixed-order read-sum) ----
    float q[16];
    #pragma unroll
    for (int k = 0; k < 16; ++k) q[k] = cbs[k];
    #pragma unroll
    for (int ww = 0; ww < 4; ++ww) {
      #pragma unroll
      for (int c = 0; c < 4; ++c) {
        const float4 pv = parts4[(ww*4 + b)*4 + c];
        q[4*c+0] += pv.x; q[4*c+1] += pv.y; q[4*c+2] += pv.z; q[4*c+3] += pv.w;
      }
    }
    float ce[16];
    #pragma unroll
    for (int k = 0; k < 15; ++k) ce[k] = __expf(q[k]);
    const float e0 = (ce[0]+ce[1]) + (ce[2]+ce[3]);
    const float e1 = (ce[4]+ce[5]) + (ce[6]+ce[7]);
    const float e2 = (ce[8]+ce[9]) + (ce[10]+ce[11]);
    const float e3 = (ce[12]+ce[13]) + ce[14];
    const float rs = 1.f / ((e0+e1) + (e2+e3));
    #pragma unroll
    for (int k = 0; k < 15; ++k) ce[k] *= rs;
    ce[15] = 0.f;
    unsigned cepk[8];
    #pragma unroll
    for (int j = 0; j < 8; ++j)
      cepk[j] = ((unsigned)bf16bits(ce[2*j+1]) << 16) | (unsigned)bf16bits(ce[2*j]);

    // ---- t-build + matvec partials, d-range per chunk ----
    float rv[5] = {0.f, 0.f, 0.f, 0.f, 0.f};
    if      (chunk == 0) tmv_part<0, 2>(m4u, cepk, stat, ii, b, swz, rv);
    else if (chunk == 1) tmv_part<2, 2>(m4u, cepk, stat, ii, b, swz, rv);
    else if (chunk == 2) tmv_part<4, 2>(m4u, cepk, stat, ii, b, swz, rv);
    else                 tmv_part<6, 1>(m4u, cepk, stat, ii, b, swz, rv);

    if (valid) {
      #pragma unroll
      for (int v = 0; v < 5; ++v) red[chunk*1280 + v*256 + ii*4 + b] = rv[v];
    }
    __syncthreads();   // B2

    // ---- combine (front: carries; c3: stores o4..o7) ----
    if (chunk == 0 || chunk == 3) {
      const float ctrl_u = ctl[par*528 + b*132 + ii];
      const float ctrl_l = ctl[par*528 + b*132 + 60 + ii];
      const int rb = ii*4 + b;
      float nmu = ctrl_u, nml = ctrl_l, ncu = tcu_r, ncl = tcl_r, ncs = 0.f;
      #pragma unroll
      for (int c = 0; c < 4; ++c) {
        nmu += red[c*1280 + 0*256 + rb];
        nml += red[c*1280 + 1*256 + rb];
        ncu += red[c*1280 + 2*256 + rb];
        ncl += red[c*1280 + 3*256 + rb];
        ncs += red[c*1280 + 4*256 + rb];
      }
      if (chunk == 3) {
        if (valid) {
          const long ob120 = ((long)gb*TT + t)*120;
          const long ob60  = ((long)gb*TT + t)*60;
          o4[ob120 + ii]      = nmu;
          o4[ob120 + 60 + ii] = nml;
          o5[ob60 + ii] = ncu;
          o6[ob60 + ii] = ncl;
          o7[ob60 + ii] = ncs;
        }
      } else {
        mu_c = nmu; ml_c = nml; cu_c = ncu; cl_c = ncl; cs_c = ncs;
      }
    }
    // races (proven in rounds 8/11/14): stat written pre-B1(t), read until
    // B2(t), next write after B2(t); parts written pre-B1(t), read pre-B2(t),
    // next write after B2(t); ctl parity-buffered; red written pre-B2(t),
    // read post-B2(t), next write after B1(t+1).
  }
}

} // namespace

extern "C" void kernel_launch(void* const* d_in, const int* in_sizes, int n_in,
                              void* d_out, int out_size, void* d_ws, size_t ws_size,
                              hipStream_t stream) {
  (void)in_sizes; (void)n_in; (void)d_ws; (void)ws_size; (void)out_size;
  const float* lob  = (const float*)d_in[0];
  const float* ovr  = (const float*)d_in[1];
  const float* actp = (const float*)d_in[2];
  const float* im   = (const float*)d_in[3];
  const float* icu  = (const float*)d_in[4];
  const float* icl  = (const float*)d_in[5];
  const float* ics  = (const float*)d_in[6];
  const float* tm11 = (const float*)d_in[7];
  const float* tm12 = (const float*)d_in[8];
  const float* tm21 = (const float*)d_in[9];
  const float* tm22 = (const float*)d_in[10];
  const float* cw   = (const float*)d_in[11];
  const float* cb   = (const float*)d_in[12];
  const float* w1   = (const float*)d_in[13];
  const float* b1   = (const float*)d_in[14];
  const float* w2   = (const float*)d_in[15];
  const float* b2   = (const float*)d_in[16];
  const float* ltc  = (const float*)d_in[17];

  acrkn<<<dim3(256), dim3(1024), 0, stream>>>(
      lob, ovr, actp, im, icu, icl, ics,
      tm11, tm12, tm21, tm22, cw, cb, w1, b1, w2, b2, ltc,
      (float*)d_out);
}